// Round 12
// baseline (109.734 us; speedup 1.0000x reference)
//
#include <hip/hip_runtime.h>

#define N_NODES  100000
#define N_EDGES  1600000
#define N_GRAPHS 128
#define DD       64
#define EPSV     1e-5f

#define BSH      5          // bucket = dst >> 5  (32 nodes per bucket)
#define BMASK    31
#define NBUCK    3125       // 100000/32 exactly
#define CAPB     768        // slab capacity: mean 512, sigma 22.6 -> 11 sigma margin

#define THRP     1024       // scatter block threads
#define EPT      8          // edges per thread -> 196 blocks (2x CU coverage vs EPT=16)
#define BLKE     (THRP*EPT) // 8192
#define NBLK     ((N_EDGES + BLKE - 1) / BLKE)   // 196

// workspace byte offsets
#define O_CUR   0u          // int[NBUCK*16]
#define O_BKT   200704u     // int[NBUCK*CAPB] packed (dstlo<<17)|src
#define O_GACC  9801216u    // float[G*D]
#define O_XB    9834496u    // ushort[N_NODES*DD]  bf16 copy of x
#define O_WTF   22634496u   // ushort[1024*8]  B-operand in MFMA fragment layout (16 KB)
#define WS_NEED (O_WTF + 16384u)

typedef __attribute__((ext_vector_type(8))) short bf16x8;
typedef __attribute__((ext_vector_type(4))) float f32x4;

__device__ __forceinline__ ushort bf16rne(float f) {
  uint u = __float_as_uint(f);
  return (ushort)((u + 0x7FFFu + ((u >> 16) & 1u)) >> 16);
}
__device__ __forceinline__ uint pk2(float lo, float hi) {
  return (uint)bf16rne(lo) | ((uint)bf16rne(hi) << 16);
}

// block-staged two-pass scatter + fused fp32->bf16 cast of x (phase 0, grid-stride)
// + block 0 builds the MFMA B-operand fragment image wtf.
// hist[] is reused in place: counts -> (after reservation) live slab cursor.
__global__ __launch_bounds__(1024) void scatP_k(const int* __restrict__ ei, int* __restrict__ cur,
                                                int* __restrict__ bkt,
                                                const float* __restrict__ x, ushort* __restrict__ xb,
                                                const float* __restrict__ Wself,
                                                const float* __restrict__ Wneigh,
                                                ushort* __restrict__ wtf) {
  __shared__ int hist[NBUCK];
  int t = threadIdx.x;
  if (blockIdx.x == 0) {
    // fragment f=(nt,tile,ks,lane): 8 bf16 of WT[nt*32+tile*16+(lane&15)][ks*32+(lane>>4)*8+j]
    int lane = t & 63, ks = (t >> 6) & 3, tile = (t >> 8) & 1, nt = t >> 9;
    int brow = (nt << 5) + (tile << 4) + (lane & 15);
    int k0 = (ks << 5) + (((lane >> 4) & 3) << 3);
    uint4 o;
    uint p[4];
#pragma unroll
    for (int jj = 0; jj < 4; ++jj) {
      int k = k0 + jj * 2;
      float w0 = (k < 64)     ? Wself[k * DD + brow]       : Wneigh[(k - 64) * DD + brow];
      float w1 = (k + 1 < 64) ? Wself[(k + 1) * DD + brow] : Wneigh[(k - 63) * DD + brow];
      p[jj] = pk2(w0, w1);
    }
    o.x = p[0]; o.y = p[1]; o.z = p[2]; o.w = p[3];
    ((uint4*)wtf)[t] = o;
  }
  for (int i = blockIdx.x * THRP + t; i < N_NODES * DD / 4; i += NBLK * THRP) {
    float4 v = ((const float4*)x)[i];
    uint4 u = *(const uint4*)&v;
    ushort4 o;
    o.x = (ushort)((u.x + 0x7FFFu + ((u.x >> 16) & 1)) >> 16);
    o.y = (ushort)((u.y + 0x7FFFu + ((u.y >> 16) & 1)) >> 16);
    o.z = (ushort)((u.z + 0x7FFFu + ((u.z >> 16) & 1)) >> 16);
    o.w = (ushort)((u.w + 0x7FFFu + ((u.w >> 16) & 1)) >> 16);
    ((ushort4*)xb)[i] = o;
  }
  for (int i = t; i < NBUCK; i += THRP) hist[i] = 0;
  __syncthreads();
  int e0 = blockIdx.x * BLKE;
  int pk[EPT], bn[EPT];
#pragma unroll
  for (int j = 0; j < EPT; ++j) {
    int e = e0 + j * THRP + t;
    bn[j] = -1;
    if (e < N_EDGES) {
      int s = ei[e], d = ei[N_EDGES + e];
      bn[j] = d >> BSH;
      pk[j] = s | ((d & BMASK) << 17);
      atomicAdd(&hist[bn[j]], 1);
    }
  }
  __syncthreads();
  for (int b = t; b < NBUCK; b += THRP) {     // each b handled by exactly one thread
    int c = hist[b];
    hist[b] = c ? atomicAdd(&cur[b * 16], c) : 0;   // count -> slab-relative base (live cursor)
  }
  __syncthreads();
#pragma unroll
  for (int j = 0; j < EPT; ++j) {
    if (bn[j] >= 0) {
      int sp = atomicAdd(&hist[bn[j]], 1);    // slab-relative position
      if (sp < CAPB) bkt[bn[j] * CAPB + sp] = pk[j];
    }
  }
}

// FUSED per-bucket kernel: counting-sort -> pull-based mean (bf16, 4-deep fat gathers)
// -> MFMA combine with register B (global fragment loads) -> pool/residual/LN/ReLU.
__global__ __launch_bounds__(256, 8) void aggM_k(const float* __restrict__ x,
                                                 const ushort* __restrict__ xb,
                                                 const int* __restrict__ cur,
                                                 const int* __restrict__ bkt,
                                                 const ushort* __restrict__ wtf,
                                                 const float* __restrict__ bvec,
                                                 const float* __restrict__ gamma,
                                                 const float* __restrict__ beta,
                                                 const int* __restrict__ batch,
                                                 float* __restrict__ gacc,
                                                 float* __restrict__ out) {
  __shared__ short As[32 * 128];    // 8KB: A=[xb|h] bf16 swizzled; overlaid by C fp32 after MFMA
  __shared__ int sorted[CAPB];      // 3KB
  __shared__ int hist[32], startc[32], curl[32];
  int t = threadIdx.x;
  int b = blockIdx.x;
  int node0 = b << BSH;
  if (t < 32) hist[t] = 0;
  // stage A x-part (k=0..63): contiguous 4KB read of this bucket's xb rows
  {
    uint4 v = ((const uint4*)(xb + (size_t)node0 * DD))[t];   // t = r*8 + c
    uint r = (uint)t >> 3, c = (uint)t & 7;
    *(uint4*)((char*)As + r * 256u + ((c * 16u) ^ ((r & 7u) << 4))) = v;
  }
  __syncthreads();
  int n = cur[b * 16];
  if (n > CAPB) n = CAPB;
  int boff = b * CAPB;
  int w0 = -1, w1 = -1, w2 = -1;
  if (t < n)       { w0 = bkt[boff + t];       atomicAdd(&hist[w0 >> 17], 1); }
  if (t + 256 < n) { w1 = bkt[boff + t + 256]; atomicAdd(&hist[w1 >> 17], 1); }
  if (t + 512 < n) { w2 = bkt[boff + t + 512]; atomicAdd(&hist[w2 >> 17], 1); }
  __syncthreads();
  if (t < 32) startc[t] = hist[t];
  __syncthreads();
  for (int off = 1; off < 32; off <<= 1) {
    int v = 0;
    if (t < 32) { v = startc[t]; if (t >= off) v += startc[t - off]; }
    __syncthreads();
    if (t < 32) startc[t] = v;
    __syncthreads();
  }
  if (t < 32) { int ex = startc[t] - hist[t]; startc[t] = ex; curl[t] = ex; }
  __syncthreads();
  if (w0 >= 0) { int p = atomicAdd(&curl[w0 >> 17], 1); sorted[p] = w0 & 0x1FFFF; }
  if (w1 >= 0) { int p = atomicAdd(&curl[w1 >> 17], 1); sorted[p] = w1 & 0x1FFFF; }
  if (w2 >= 0) { int p = atomicAdd(&curl[w2 >> 17], 1); sorted[p] = w2 & 0x1FFFF; }
  __syncthreads();
  int wl   = __builtin_amdgcn_readfirstlane(t >> 6);
  int lane = t & 63;
  int g    = lane >> 4;     // edge-group 0..3
  int sub  = lane & 15;     // dim group: dims [sub*4, sub*4+4)
  const uint2* xb2 = (const uint2*)xb;   // row stride = 16 uint2 (64 ushorts)
  // pull aggregation: 4 edges per instruction x 4 loads in flight; mean -> A k=64..127
  for (int r = wl; r < 32; r += 4) {
    int s0 = startc[r], dg = hist[r];
    int dgm1 = dg > 0 ? dg - 1 : 0;
    float a0 = 0.f, a1 = 0.f, a2 = 0.f, a3 = 0.f;
    for (int j = 0; j < dg; j += 16) {
      int e0 = j + g, e1 = j + 4 + g, e2 = j + 8 + g, e3 = j + 12 + g;
      int i0 = sorted[s0 + (e0 < dg ? e0 : dgm1)];
      int i1 = sorted[s0 + (e1 < dg ? e1 : dgm1)];
      int i2 = sorted[s0 + (e2 < dg ? e2 : dgm1)];
      int i3 = sorted[s0 + (e3 < dg ? e3 : dgm1)];
      uint2 u0 = xb2[(size_t)i0 * 16 + sub];
      uint2 u1 = xb2[(size_t)i1 * 16 + sub];
      uint2 u2 = xb2[(size_t)i2 * 16 + sub];
      uint2 u3 = xb2[(size_t)i3 * 16 + sub];
      if (e0 >= dg) { u0.x = 0u; u0.y = 0u; }
      if (e1 >= dg) { u1.x = 0u; u1.y = 0u; }
      if (e2 >= dg) { u2.x = 0u; u2.y = 0u; }
      if (e3 >= dg) { u3.x = 0u; u3.y = 0u; }
      a0 += (__uint_as_float(u0.x << 16) + __uint_as_float(u1.x << 16))
          + (__uint_as_float(u2.x << 16) + __uint_as_float(u3.x << 16));
      a1 += (__uint_as_float(u0.x & 0xFFFF0000u) + __uint_as_float(u1.x & 0xFFFF0000u))
          + (__uint_as_float(u2.x & 0xFFFF0000u) + __uint_as_float(u3.x & 0xFFFF0000u));
      a2 += (__uint_as_float(u0.y << 16) + __uint_as_float(u1.y << 16))
          + (__uint_as_float(u2.y << 16) + __uint_as_float(u3.y << 16));
      a3 += (__uint_as_float(u0.y & 0xFFFF0000u) + __uint_as_float(u1.y & 0xFFFF0000u))
          + (__uint_as_float(u2.y & 0xFFFF0000u) + __uint_as_float(u3.y & 0xFFFF0000u));
    }
#pragma unroll
    for (int off = 16; off <= 32; off <<= 1) {
      a0 += __shfl_xor(a0, off);
      a1 += __shfl_xor(a1, off);
      a2 += __shfl_xor(a2, off);
      a3 += __shfl_xor(a3, off);
    }
    if (g == 0) {
      float inv = 1.f / fmaxf((float)dg, 1.f);
      uint2 pw;
      pw.x = pk2(a0 * inv, a1 * inv);
      pw.y = pk2(a2 * inv, a3 * inv);
      uint rr = (uint)r;
      *(uint2*)((char*)As + rr * 256u + ((128u + (uint)sub * 8u) ^ ((rr & 7u) << 4))) = pw;
    }
  }
  __syncthreads();
  // MFMA combine: wave -> (mrow, n-tile pair); B fragments streamed from global (L2-hot),
  // unroll 1 keeps the loads in-loop so peak VGPR stays within the 8-blocks/CU budget.
  f32x4 acc0 = {0.f, 0.f, 0.f, 0.f}, acc1 = {0.f, 0.f, 0.f, 0.f};
  uint mrow  = (uint)(wl >> 1) << 4;   // 0 / 16
  int  nt    = wl & 1;
  uint arow  = mrow + (uint)(lane & 15);
  uint kc    = ((uint)(lane >> 4)) * 16u;   // byte offset of this lane's k-chunk
#pragma unroll 1
  for (int ks = 0; ks < 4; ++ks) {
    uint kb = (uint)ks * 64u + kc;
    bf16x8 af = *(const bf16x8*)((const char*)As + arow * 256u + (kb ^ ((arow & 7u) << 4)));
    bf16x8 b0 = *(const bf16x8*)(wtf + (size_t)(((nt * 2 + 0) * 4 + ks) * 64 + lane) * 8);
    bf16x8 b1 = *(const bf16x8*)(wtf + (size_t)(((nt * 2 + 1) * 4 + ks) * 64 + lane) * 8);
    acc0 = __builtin_amdgcn_mfma_f32_16x16x32_bf16(af, b0, acc0, 0, 0, 0);
    acc1 = __builtin_amdgcn_mfma_f32_16x16x32_bf16(af, b1, acc1, 0, 0, 0);
  }
  __syncthreads();            // all A reads done -> safe to overlay C
  float* Cl = (float*)As;     // C fp32 [32][64], swizzled, overlays A (same 8KB)
  {
    uint nbase = (uint)nt << 5;
    uint rr = mrow + (((uint)(lane >> 4)) << 2);
    uint cc = nbase + (uint)(lane & 15);
#pragma unroll
    for (int j = 0; j < 4; ++j) {
      uint rj = rr + (uint)j;
      *(float*)((char*)Cl + rj * 256u + ((cc * 4u) ^ ((rj & 7u) << 4)))          = acc0[j];
      *(float*)((char*)Cl + rj * 256u + (((cc + 16u) * 4u) ^ ((rj & 7u) << 4)))  = acc1[j];
    }
  }
  __syncthreads();
  // epilogue: bias, graph pooling (sorted batch), residual (fp32 x), LN, ReLU
  float bv  = bvec[lane];
  float gv  = gamma[lane];
  float btv = beta[lane];
  int r0 = wl * 8;
  int gprev = -1; float pool = 0.f;
#pragma unroll
  for (int m = 0; m < 8; ++m) {
    uint r = (uint)(r0 + m);
    int node = node0 + r0 + m;
    float cval = *(const float*)((const char*)Cl + r * 256u + (((uint)lane * 4u) ^ ((r & 7u) << 4)));
    float tmp = cval + bv;
    int gi = batch[node];
    if (gi != gprev) {
      if (gprev >= 0) atomicAdd(&gacc[gprev * DD + lane], pool);
      pool = 0.f; gprev = gi;
    }
    pool += tmp;
    float val = tmp + x[(size_t)node * DD + lane];
    float s = val;
    for (int off = 32; off; off >>= 1) s += __shfl_xor(s, off);
    float mu  = s * (1.f / 64.f);
    float dlt = val - mu;
    float ss  = dlt * dlt;
    for (int off = 32; off; off >>= 1) ss += __shfl_xor(ss, off);
    float rstd = rsqrtf(ss * (1.f / 64.f) + EPSV);
    float o = dlt * rstd * gv + btv;
    out[(size_t)node * DD + lane] = fmaxf(o, 0.f);
  }
  if (gprev >= 0) atomicAdd(&gacc[gprev * DD + lane], pool);
}

__global__ __launch_bounds__(256) void graph_k(const float* __restrict__ gacc, const float* __restrict__ gemb,
                                               const float* __restrict__ gamma, const float* __restrict__ beta,
                                               float* __restrict__ out) {
  int lane = threadIdx.x & 63;
  int w = blockIdx.x * 4 + (threadIdx.x >> 6);
  if (w >= N_GRAPHS) return;
  float v = gacc[w * DD + lane] + gemb[w * DD + lane];
  float gv = gamma[lane], btv = beta[lane];
#pragma unroll
  for (int it = 0; it < 2; ++it) {
    float s = v;
    for (int off = 32; off; off >>= 1) s += __shfl_xor(s, off);
    float mu  = s * (1.f / 64.f);
    float d   = v - mu;
    float ss  = d * d;
    for (int off = 32; off; off >>= 1) ss += __shfl_xor(ss, off);
    v = d * rsqrtf(ss * (1.f / 64.f) + EPSV) * gv + btv;
  }
  out[(size_t)N_NODES * DD + w * DD + lane] = v;
}

extern "C" void kernel_launch(void* const* d_in, const int* in_sizes, int n_in,
                              void* d_out, int out_size, void* d_ws, size_t ws_size,
                              hipStream_t stream) {
  const float* x      = (const float*)d_in[0];
  const int*   ei     = (const int*)d_in[1];
  const int*   batch  = (const int*)d_in[2];
  const float* gemb   = (const float*)d_in[3];
  const float* Wself  = (const float*)d_in[4];
  const float* Wneigh = (const float*)d_in[5];
  const float* bvec   = (const float*)d_in[6];
  const float* gamma  = (const float*)d_in[7];
  const float* beta   = (const float*)d_in[8];

  char* ws = (char*)d_ws;
  int*    cur  = (int*)(ws + O_CUR);
  int*    bkt  = (int*)(ws + O_BKT);
  float*  gacc = (float*)(ws + O_GACC);
  ushort* xb   = (ushort*)(ws + O_XB);
  ushort* wtf  = (ushort*)(ws + O_WTF);
  float*  outf = (float*)d_out;

  hipMemsetAsync(cur, 0, NBUCK * 16 * sizeof(int), stream);
  hipMemsetAsync(gacc, 0, N_GRAPHS * DD * sizeof(float), stream);

  scatP_k<<<NBLK, THRP, 0, stream>>>(ei, cur, bkt, x, xb, Wself, Wneigh, wtf);
  aggM_k <<<NBUCK, 256, 0, stream>>>(x, xb, cur, bkt, wtf, bvec, gamma, beta,
                                     batch, gacc, outf);
  graph_k<<<N_GRAPHS / 4, 256, 0, stream>>>(gacc, gemb, gamma, beta, outf);
}

// Round 13
// 97.612 us; speedup vs baseline: 1.1242x; 1.1242x over previous
//
#include <hip/hip_runtime.h>

#define N_NODES  100000
#define N_EDGES  1600000
#define N_GRAPHS 128
#define DD       64
#define EPSV     1e-5f

#define BSH      5          // bucket = dst >> 5  (32 nodes per bucket)
#define BMASK    31
#define NBUCK    3125       // 100000/32 exactly
#define CAPB     768        // slab capacity: mean 512, sigma 22.6 -> 11 sigma margin

#define THRP     1024       // scatter block threads
#define EPT      16         // edges per thread (98 blocks — R11 known-good)
#define BLKE     (THRP*EPT) // 16384
#define NBLK     ((N_EDGES + BLKE - 1) / BLKE)   // 98

// workspace byte offsets
#define O_CUR   0u          // int[NBUCK*16]
#define O_BKT   200704u     // int[NBUCK*CAPB] packed (dstlo<<17)|src
#define O_GACC  9801216u    // float[G*D]
#define O_XB    9834496u    // ushort[N_NODES*DD]  bf16 copy of x
#define O_WTF   22634496u   // ushort[1024*8]  B-operand in MFMA fragment layout (16 KB)
#define WS_NEED (O_WTF + 16384u)

typedef __attribute__((ext_vector_type(8))) short bf16x8;
typedef __attribute__((ext_vector_type(4))) float f32x4;

__device__ __forceinline__ ushort bf16rne(float f) {
  uint u = __float_as_uint(f);
  return (ushort)((u + 0x7FFFu + ((u >> 16) & 1u)) >> 16);
}
__device__ __forceinline__ uint pk2(float lo, float hi) {
  return (uint)bf16rne(lo) | ((uint)bf16rne(hi) << 16);
}

// full-grid fp32->bf16 cast of x + zero-init of cur and gacc (replaces 2 memsets)
__global__ __launch_bounds__(256) void cast_k(const float* __restrict__ x, ushort* __restrict__ xb,
                                              int* __restrict__ cur, float* __restrict__ gacc) {
  int i = blockIdx.x * 256 + threadIdx.x;      // grid 6250*256 = 1.6M = N_NODES*DD/4 exactly
  if (i < NBUCK * 16) cur[i] = 0;
  if (i < N_GRAPHS * DD) gacc[i] = 0.f;
  float4 v = ((const float4*)x)[i];
  uint4 u = *(const uint4*)&v;
  ushort4 o;
  o.x = (ushort)((u.x + 0x7FFFu + ((u.x >> 16) & 1)) >> 16);
  o.y = (ushort)((u.y + 0x7FFFu + ((u.y >> 16) & 1)) >> 16);
  o.z = (ushort)((u.z + 0x7FFFu + ((u.z >> 16) & 1)) >> 16);
  o.w = (ushort)((u.w + 0x7FFFu + ((u.w >> 16) & 1)) >> 16);
  ((ushort4*)xb)[i] = o;
}

// block-staged two-pass scatter; block 0 also builds the MFMA B-operand image wtf.
// hist[] reused in place: counts -> (after reservation) live slab cursor.
__global__ __launch_bounds__(1024) void scatP_k(const int* __restrict__ ei, int* __restrict__ cur,
                                                int* __restrict__ bkt,
                                                const float* __restrict__ Wself,
                                                const float* __restrict__ Wneigh,
                                                ushort* __restrict__ wtf) {
  __shared__ int hist[NBUCK];
  int t = threadIdx.x;
  if (blockIdx.x == 0) {
    // fragment f=(nt,tile,ks,lane): 8 bf16 of WT[nt*32+tile*16+(lane&15)][ks*32+(lane>>4)*8+j]
    int lane = t & 63, ks = (t >> 6) & 3, tile = (t >> 8) & 1, nt = t >> 9;
    int brow = (nt << 5) + (tile << 4) + (lane & 15);
    int k0 = (ks << 5) + (((lane >> 4) & 3) << 3);
    uint4 o;
    uint p[4];
#pragma unroll
    for (int jj = 0; jj < 4; ++jj) {
      int k = k0 + jj * 2;
      float w0 = (k < 64)     ? Wself[k * DD + brow]       : Wneigh[(k - 64) * DD + brow];
      float w1 = (k + 1 < 64) ? Wself[(k + 1) * DD + brow] : Wneigh[(k - 63) * DD + brow];
      p[jj] = pk2(w0, w1);
    }
    o.x = p[0]; o.y = p[1]; o.z = p[2]; o.w = p[3];
    ((uint4*)wtf)[t] = o;
  }
  for (int i = t; i < NBUCK; i += THRP) hist[i] = 0;
  __syncthreads();
  int e0 = blockIdx.x * BLKE;
  int pk[EPT], bn[EPT];
#pragma unroll
  for (int j = 0; j < EPT; ++j) {
    int e = e0 + j * THRP + t;
    bn[j] = -1;
    if (e < N_EDGES) {
      int s = ei[e], d = ei[N_EDGES + e];
      bn[j] = d >> BSH;
      pk[j] = s | ((d & BMASK) << 17);
      atomicAdd(&hist[bn[j]], 1);
    }
  }
  __syncthreads();
  for (int b = t; b < NBUCK; b += THRP) {     // each b handled by exactly one thread
    int c = hist[b];
    hist[b] = c ? atomicAdd(&cur[b * 16], c) : 0;   // count -> live slab cursor
  }
  __syncthreads();
#pragma unroll
  for (int j = 0; j < EPT; ++j) {
    if (bn[j] >= 0) {
      int sp = atomicAdd(&hist[bn[j]], 1);    // slab-relative position
      if (sp < CAPB) bkt[bn[j] * CAPB + sp] = pk[j];
    }
  }
}

// FUSED per-bucket kernel: counting-sort -> pull-based mean (bf16, 4-deep fat gathers)
// -> MFMA combine with register B (global fragment loads) -> pool/residual/LN/ReLU.
__global__ __launch_bounds__(256, 8) void aggM_k(const float* __restrict__ x,
                                                 const ushort* __restrict__ xb,
                                                 const int* __restrict__ cur,
                                                 const int* __restrict__ bkt,
                                                 const ushort* __restrict__ wtf,
                                                 const float* __restrict__ bvec,
                                                 const float* __restrict__ gamma,
                                                 const float* __restrict__ beta,
                                                 const int* __restrict__ batch,
                                                 float* __restrict__ gacc,
                                                 float* __restrict__ out) {
  __shared__ short As[32 * 128];    // 8KB: A=[xb|h] bf16 swizzled; overlaid by C fp32 after MFMA
  __shared__ int sorted[CAPB];      // 3KB
  __shared__ int hist[32], startc[32], curl[32];
  int t = threadIdx.x;
  int b = blockIdx.x;
  int node0 = b << BSH;
  if (t < 32) hist[t] = 0;
  // stage A x-part (k=0..63): contiguous 4KB read of this bucket's xb rows
  {
    uint4 v = ((const uint4*)(xb + (size_t)node0 * DD))[t];   // t = r*8 + c
    uint r = (uint)t >> 3, c = (uint)t & 7;
    *(uint4*)((char*)As + r * 256u + ((c * 16u) ^ ((r & 7u) << 4))) = v;
  }
  __syncthreads();
  int n = cur[b * 16];
  if (n > CAPB) n = CAPB;
  int boff = b * CAPB;
  int w0 = -1, w1 = -1, w2 = -1;
  if (t < n)       { w0 = bkt[boff + t];       atomicAdd(&hist[w0 >> 17], 1); }
  if (t + 256 < n) { w1 = bkt[boff + t + 256]; atomicAdd(&hist[w1 >> 17], 1); }
  if (t + 512 < n) { w2 = bkt[boff + t + 512]; atomicAdd(&hist[w2 >> 17], 1); }
  __syncthreads();
  if (t < 32) startc[t] = hist[t];
  __syncthreads();
  for (int off = 1; off < 32; off <<= 1) {
    int v = 0;
    if (t < 32) { v = startc[t]; if (t >= off) v += startc[t - off]; }
    __syncthreads();
    if (t < 32) startc[t] = v;
    __syncthreads();
  }
  if (t < 32) { int ex = startc[t] - hist[t]; startc[t] = ex; curl[t] = ex; }
  __syncthreads();
  if (w0 >= 0) { int p = atomicAdd(&curl[w0 >> 17], 1); sorted[p] = w0 & 0x1FFFF; }
  if (w1 >= 0) { int p = atomicAdd(&curl[w1 >> 17], 1); sorted[p] = w1 & 0x1FFFF; }
  if (w2 >= 0) { int p = atomicAdd(&curl[w2 >> 17], 1); sorted[p] = w2 & 0x1FFFF; }
  __syncthreads();
  int wl   = __builtin_amdgcn_readfirstlane(t >> 6);
  int lane = t & 63;
  int g    = lane >> 4;     // edge-group 0..3
  int sub  = lane & 15;     // dim group: dims [sub*4, sub*4+4)
  const uint2* xb2 = (const uint2*)xb;   // row stride = 16 uint2 (64 ushorts)
  // pull aggregation: 4 edges per instruction x 4 loads in flight; mean -> A k=64..127
  for (int r = wl; r < 32; r += 4) {
    int s0 = startc[r], dg = hist[r];
    int dgm1 = dg > 0 ? dg - 1 : 0;
    float a0 = 0.f, a1 = 0.f, a2 = 0.f, a3 = 0.f;
    for (int j = 0; j < dg; j += 16) {
      int e0 = j + g, e1 = j + 4 + g, e2 = j + 8 + g, e3 = j + 12 + g;
      int i0 = sorted[s0 + (e0 < dg ? e0 : dgm1)];
      int i1 = sorted[s0 + (e1 < dg ? e1 : dgm1)];
      int i2 = sorted[s0 + (e2 < dg ? e2 : dgm1)];
      int i3 = sorted[s0 + (e3 < dg ? e3 : dgm1)];
      uint2 u0 = xb2[(size_t)i0 * 16 + sub];
      uint2 u1 = xb2[(size_t)i1 * 16 + sub];
      uint2 u2 = xb2[(size_t)i2 * 16 + sub];
      uint2 u3 = xb2[(size_t)i3 * 16 + sub];
      if (e0 >= dg) { u0.x = 0u; u0.y = 0u; }
      if (e1 >= dg) { u1.x = 0u; u1.y = 0u; }
      if (e2 >= dg) { u2.x = 0u; u2.y = 0u; }
      if (e3 >= dg) { u3.x = 0u; u3.y = 0u; }
      a0 += (__uint_as_float(u0.x << 16) + __uint_as_float(u1.x << 16))
          + (__uint_as_float(u2.x << 16) + __uint_as_float(u3.x << 16));
      a1 += (__uint_as_float(u0.x & 0xFFFF0000u) + __uint_as_float(u1.x & 0xFFFF0000u))
          + (__uint_as_float(u2.x & 0xFFFF0000u) + __uint_as_float(u3.x & 0xFFFF0000u));
      a2 += (__uint_as_float(u0.y << 16) + __uint_as_float(u1.y << 16))
          + (__uint_as_float(u2.y << 16) + __uint_as_float(u3.y << 16));
      a3 += (__uint_as_float(u0.y & 0xFFFF0000u) + __uint_as_float(u1.y & 0xFFFF0000u))
          + (__uint_as_float(u2.y & 0xFFFF0000u) + __uint_as_float(u3.y & 0xFFFF0000u));
    }
#pragma unroll
    for (int off = 16; off <= 32; off <<= 1) {
      a0 += __shfl_xor(a0, off);
      a1 += __shfl_xor(a1, off);
      a2 += __shfl_xor(a2, off);
      a3 += __shfl_xor(a3, off);
    }
    if (g == 0) {
      float inv = 1.f / fmaxf((float)dg, 1.f);
      uint2 pw;
      pw.x = pk2(a0 * inv, a1 * inv);
      pw.y = pk2(a2 * inv, a3 * inv);
      uint rr = (uint)r;
      *(uint2*)((char*)As + rr * 256u + ((128u + (uint)sub * 8u) ^ ((rr & 7u) << 4))) = pw;
    }
  }
  __syncthreads();
  // MFMA combine: wave -> (mrow, n-tile pair); B fragments streamed from global (L2-hot),
  // unroll 1 keeps the loads in-loop so peak VGPR stays within the 8-blocks/CU budget.
  f32x4 acc0 = {0.f, 0.f, 0.f, 0.f}, acc1 = {0.f, 0.f, 0.f, 0.f};
  uint mrow  = (uint)(wl >> 1) << 4;   // 0 / 16
  int  nt    = wl & 1;
  uint arow  = mrow + (uint)(lane & 15);
  uint kc    = ((uint)(lane >> 4)) * 16u;   // byte offset of this lane's k-chunk
#pragma unroll 1
  for (int ks = 0; ks < 4; ++ks) {
    uint kb = (uint)ks * 64u + kc;
    bf16x8 af = *(const bf16x8*)((const char*)As + arow * 256u + (kb ^ ((arow & 7u) << 4)));
    bf16x8 b0 = *(const bf16x8*)(wtf + (size_t)(((nt * 2 + 0) * 4 + ks) * 64 + lane) * 8);
    bf16x8 b1 = *(const bf16x8*)(wtf + (size_t)(((nt * 2 + 1) * 4 + ks) * 64 + lane) * 8);
    acc0 = __builtin_amdgcn_mfma_f32_16x16x32_bf16(af, b0, acc0, 0, 0, 0);
    acc1 = __builtin_amdgcn_mfma_f32_16x16x32_bf16(af, b1, acc1, 0, 0, 0);
  }
  __syncthreads();            // all A reads done -> safe to overlay C
  float* Cl = (float*)As;     // C fp32 [32][64], swizzled, overlays A (same 8KB)
  {
    uint nbase = (uint)nt << 5;
    uint rr = mrow + (((uint)(lane >> 4)) << 2);
    uint cc = nbase + (uint)(lane & 15);
#pragma unroll
    for (int j = 0; j < 4; ++j) {
      uint rj = rr + (uint)j;
      *(float*)((char*)Cl + rj * 256u + ((cc * 4u) ^ ((rj & 7u) << 4)))          = acc0[j];
      *(float*)((char*)Cl + rj * 256u + (((cc + 16u) * 4u) ^ ((rj & 7u) << 4)))  = acc1[j];
    }
  }
  __syncthreads();
  // epilogue: bias, graph pooling (sorted batch), residual (fp32 x), LN, ReLU
  float bv  = bvec[lane];
  float gv  = gamma[lane];
  float btv = beta[lane];
  int r0 = wl * 8;
  int gprev = -1; float pool = 0.f;
#pragma unroll
  for (int m = 0; m < 8; ++m) {
    uint r = (uint)(r0 + m);
    int node = node0 + r0 + m;
    float cval = *(const float*)((const char*)Cl + r * 256u + (((uint)lane * 4u) ^ ((r & 7u) << 4)));
    float tmp = cval + bv;
    int gi = batch[node];
    if (gi != gprev) {
      if (gprev >= 0) atomicAdd(&gacc[gprev * DD + lane], pool);
      pool = 0.f; gprev = gi;
    }
    pool += tmp;
    float val = tmp + x[(size_t)node * DD + lane];
    float s = val;
    for (int off = 32; off; off >>= 1) s += __shfl_xor(s, off);
    float mu  = s * (1.f / 64.f);
    float dlt = val - mu;
    float ss  = dlt * dlt;
    for (int off = 32; off; off >>= 1) ss += __shfl_xor(ss, off);
    float rstd = rsqrtf(ss * (1.f / 64.f) + EPSV);
    float o = dlt * rstd * gv + btv;
    out[(size_t)node * DD + lane] = fmaxf(o, 0.f);
  }
  if (gprev >= 0) atomicAdd(&gacc[gprev * DD + lane], pool);
}

__global__ __launch_bounds__(256) void graph_k(const float* __restrict__ gacc, const float* __restrict__ gemb,
                                               const float* __restrict__ gamma, const float* __restrict__ beta,
                                               float* __restrict__ out) {
  int lane = threadIdx.x & 63;
  int w = blockIdx.x * 4 + (threadIdx.x >> 6);
  if (w >= N_GRAPHS) return;
  float v = gacc[w * DD + lane] + gemb[w * DD + lane];
  float gv = gamma[lane], btv = beta[lane];
#pragma unroll
  for (int it = 0; it < 2; ++it) {
    float s = v;
    for (int off = 32; off; off >>= 1) s += __shfl_xor(s, off);
    float mu  = s * (1.f / 64.f);
    float d   = v - mu;
    float ss  = d * d;
    for (int off = 32; off; off >>= 1) ss += __shfl_xor(ss, off);
    v = d * rsqrtf(ss * (1.f / 64.f) + EPSV) * gv + btv;
  }
  out[(size_t)N_NODES * DD + w * DD + lane] = v;
}

extern "C" void kernel_launch(void* const* d_in, const int* in_sizes, int n_in,
                              void* d_out, int out_size, void* d_ws, size_t ws_size,
                              hipStream_t stream) {
  const float* x      = (const float*)d_in[0];
  const int*   ei     = (const int*)d_in[1];
  const int*   batch  = (const int*)d_in[2];
  const float* gemb   = (const float*)d_in[3];
  const float* Wself  = (const float*)d_in[4];
  const float* Wneigh = (const float*)d_in[5];
  const float* bvec   = (const float*)d_in[6];
  const float* gamma  = (const float*)d_in[7];
  const float* beta   = (const float*)d_in[8];

  char* ws = (char*)d_ws;
  int*    cur  = (int*)(ws + O_CUR);
  int*    bkt  = (int*)(ws + O_BKT);
  float*  gacc = (float*)(ws + O_GACC);
  ushort* xb   = (ushort*)(ws + O_XB);
  ushort* wtf  = (ushort*)(ws + O_WTF);
  float*  outf = (float*)d_out;

  cast_k <<<N_NODES * DD / 4 / 256, 256, 0, stream>>>(x, xb, cur, gacc);
  scatP_k<<<NBLK, THRP, 0, stream>>>(ei, cur, bkt, Wself, Wneigh, wtf);
  aggM_k <<<NBUCK, 256, 0, stream>>>(x, xb, cur, bkt, wtf, bvec, gamma, beta,
                                     batch, gacc, outf);
  graph_k<<<N_GRAPHS / 4, 256, 0, stream>>>(gacc, gemb, gamma, beta, outf);
}

// Round 14
// 95.336 us; speedup vs baseline: 1.1510x; 1.0239x over previous
//
#include <hip/hip_runtime.h>

#define N_NODES  100000
#define N_EDGES  1600000
#define N_GRAPHS 128
#define DD       64
#define EPSV     1e-5f

#define BSH      5          // bucket = dst >> 5  (32 nodes per bucket)
#define BMASK    31
#define NBUCK    3125       // 100000/32 exactly
#define CAPB     768        // slab capacity: mean 512, sigma 22.6 -> 11 sigma margin

#define THRP     1024       // scatter block threads
#define EPT      16         // edges per thread (98 blocks — known-good)
#define BLKE     (THRP*EPT) // 16384
#define NBLK     ((N_EDGES + BLKE - 1) / BLKE)   // 98

// workspace byte offsets
#define O_CUR   0u          // int[NBUCK*16]
#define O_BKT   200704u     // int[NBUCK*CAPB] packed (dstlo<<17)|src
#define O_GACC  9801216u    // float[G*D]
#define O_XB    9834496u    // ushort[N_NODES*DD]  bf16 copy of x
#define O_WTF   22634496u   // ushort[1024*8]  B-operand in MFMA fragment layout (16 KB)
#define WS_NEED (O_WTF + 16384u)

typedef __attribute__((ext_vector_type(8))) short bf16x8;
typedef __attribute__((ext_vector_type(4))) float f32x4;

__device__ __forceinline__ ushort bf16rne(float f) {
  uint u = __float_as_uint(f);
  return (ushort)((u + 0x7FFFu + ((u >> 16) & 1u)) >> 16);
}
__device__ __forceinline__ uint pk2(float lo, float hi) {
  return (uint)bf16rne(lo) | ((uint)bf16rne(hi) << 16);
}

// full-grid fp32->bf16 cast of x + zero-init of cur and gacc (replaces 2 memsets)
__global__ __launch_bounds__(256) void cast_k(const float* __restrict__ x, ushort* __restrict__ xb,
                                              int* __restrict__ cur, float* __restrict__ gacc) {
  int i = blockIdx.x * 256 + threadIdx.x;      // grid 6250*256 = 1.6M = N_NODES*DD/4 exactly
  if (i < NBUCK * 16) cur[i] = 0;
  if (i < N_GRAPHS * DD) gacc[i] = 0.f;
  float4 v = ((const float4*)x)[i];
  uint4 u = *(const uint4*)&v;
  ushort4 o;
  o.x = (ushort)((u.x + 0x7FFFu + ((u.x >> 16) & 1)) >> 16);
  o.y = (ushort)((u.y + 0x7FFFu + ((u.y >> 16) & 1)) >> 16);
  o.z = (ushort)((u.z + 0x7FFFu + ((u.z >> 16) & 1)) >> 16);
  o.w = (ushort)((u.w + 0x7FFFu + ((u.w >> 16) & 1)) >> 16);
  ((ushort4*)xb)[i] = o;
}

// block-staged two-pass scatter; block 0 also builds the MFMA B-operand image wtf.
// hist[] reused in place: counts -> (after reservation) live slab cursor.
__global__ __launch_bounds__(1024) void scatP_k(const int* __restrict__ ei, int* __restrict__ cur,
                                                int* __restrict__ bkt,
                                                const float* __restrict__ Wself,
                                                const float* __restrict__ Wneigh,
                                                ushort* __restrict__ wtf) {
  __shared__ int hist[NBUCK];
  int t = threadIdx.x;
  if (blockIdx.x == 0) {
    // fragment f=(nt,tile,ks,lane): 8 bf16 of WT[nt*32+tile*16+(lane&15)][ks*32+(lane>>4)*8+j]
    int lane = t & 63, ks = (t >> 6) & 3, tile = (t >> 8) & 1, nt = t >> 9;
    int brow = (nt << 5) + (tile << 4) + (lane & 15);
    int k0 = (ks << 5) + (((lane >> 4) & 3) << 3);
    uint4 o;
    uint p[4];
#pragma unroll
    for (int jj = 0; jj < 4; ++jj) {
      int k = k0 + jj * 2;
      float w0 = (k < 64)     ? Wself[k * DD + brow]       : Wneigh[(k - 64) * DD + brow];
      float w1 = (k + 1 < 64) ? Wself[(k + 1) * DD + brow] : Wneigh[(k - 63) * DD + brow];
      p[jj] = pk2(w0, w1);
    }
    o.x = p[0]; o.y = p[1]; o.z = p[2]; o.w = p[3];
    ((uint4*)wtf)[t] = o;
  }
  for (int i = t; i < NBUCK; i += THRP) hist[i] = 0;
  __syncthreads();
  int e0 = blockIdx.x * BLKE;
  int pk[EPT], bn[EPT];
#pragma unroll
  for (int j = 0; j < EPT; ++j) {
    int e = e0 + j * THRP + t;
    bn[j] = -1;
    if (e < N_EDGES) {
      int s = ei[e], d = ei[N_EDGES + e];
      bn[j] = d >> BSH;
      pk[j] = s | ((d & BMASK) << 17);
      atomicAdd(&hist[bn[j]], 1);
    }
  }
  __syncthreads();
  for (int b = t; b < NBUCK; b += THRP) {     // each b handled by exactly one thread
    int c = hist[b];
    hist[b] = c ? atomicAdd(&cur[b * 16], c) : 0;   // count -> live slab cursor
  }
  __syncthreads();
#pragma unroll
  for (int j = 0; j < EPT; ++j) {
    if (bn[j] >= 0) {
      int sp = atomicAdd(&hist[bn[j]], 1);    // slab-relative position
      if (sp < CAPB) bkt[bn[j] * CAPB + sp] = pk[j];
    }
  }
}

// FUSED per-bucket kernel: counting-sort -> pull-based mean (bf16, 4-deep fat gathers)
// -> MFMA combine (register B) -> pool/residual/LN/ReLU, residual from LDS bf16 x.
__global__ __launch_bounds__(256, 8) void aggM_k(const ushort* __restrict__ xb,
                                                 const int* __restrict__ cur,
                                                 const int* __restrict__ bkt,
                                                 const ushort* __restrict__ wtf,
                                                 const float* __restrict__ bvec,
                                                 const float* __restrict__ gamma,
                                                 const float* __restrict__ beta,
                                                 const int* __restrict__ batch,
                                                 float* __restrict__ gacc,
                                                 float* __restrict__ out) {
  __shared__ short As[32 * 128];    // 8KB: A=[xb|h] bf16 swizzled; LIVE through epilogue
  __shared__ float Cbuf[32 * 65];   // 8.3KB: MFMA C, padded row stride (conflict-free reads)
  __shared__ int sorted[CAPB];      // 3KB
  __shared__ int hist[32], startc[32], curl[32];
  int t = threadIdx.x;
  int b = blockIdx.x;
  int node0 = b << BSH;
  if (t < 32) hist[t] = 0;
  // stage A x-part (k=0..63): contiguous 4KB read of this bucket's xb rows
  {
    uint4 v = ((const uint4*)(xb + (size_t)node0 * DD))[t];   // t = r*8 + c
    uint r = (uint)t >> 3, c = (uint)t & 7;
    *(uint4*)((char*)As + r * 256u + ((c * 16u) ^ ((r & 7u) << 4))) = v;
  }
  __syncthreads();
  int n = cur[b * 16];
  if (n > CAPB) n = CAPB;
  int boff = b * CAPB;
  int w0 = -1, w1 = -1, w2 = -1;
  if (t < n)       { w0 = bkt[boff + t];       atomicAdd(&hist[w0 >> 17], 1); }
  if (t + 256 < n) { w1 = bkt[boff + t + 256]; atomicAdd(&hist[w1 >> 17], 1); }
  if (t + 512 < n) { w2 = bkt[boff + t + 512]; atomicAdd(&hist[w2 >> 17], 1); }
  __syncthreads();
  if (t < 32) startc[t] = hist[t];
  __syncthreads();
  for (int off = 1; off < 32; off <<= 1) {
    int v = 0;
    if (t < 32) { v = startc[t]; if (t >= off) v += startc[t - off]; }
    __syncthreads();
    if (t < 32) startc[t] = v;
    __syncthreads();
  }
  if (t < 32) { int ex = startc[t] - hist[t]; startc[t] = ex; curl[t] = ex; }
  __syncthreads();
  if (w0 >= 0) { int p = atomicAdd(&curl[w0 >> 17], 1); sorted[p] = w0 & 0x1FFFF; }
  if (w1 >= 0) { int p = atomicAdd(&curl[w1 >> 17], 1); sorted[p] = w1 & 0x1FFFF; }
  if (w2 >= 0) { int p = atomicAdd(&curl[w2 >> 17], 1); sorted[p] = w2 & 0x1FFFF; }
  __syncthreads();
  int wl   = __builtin_amdgcn_readfirstlane(t >> 6);
  int lane = t & 63;
  int g    = lane >> 4;     // edge-group 0..3
  int sub  = lane & 15;     // dim group: dims [sub*4, sub*4+4)
  const uint2* xb2 = (const uint2*)xb;   // row stride = 16 uint2 (64 ushorts)
  // pull aggregation: 4 edges per instruction x 4 loads in flight; mean -> A k=64..127
  for (int r = wl; r < 32; r += 4) {
    int s0 = startc[r], dg = hist[r];
    int dgm1 = dg > 0 ? dg - 1 : 0;
    float a0 = 0.f, a1 = 0.f, a2 = 0.f, a3 = 0.f;
    for (int j = 0; j < dg; j += 16) {
      int e0 = j + g, e1 = j + 4 + g, e2 = j + 8 + g, e3 = j + 12 + g;
      int i0 = sorted[s0 + (e0 < dg ? e0 : dgm1)];
      int i1 = sorted[s0 + (e1 < dg ? e1 : dgm1)];
      int i2 = sorted[s0 + (e2 < dg ? e2 : dgm1)];
      int i3 = sorted[s0 + (e3 < dg ? e3 : dgm1)];
      uint2 u0 = xb2[(size_t)i0 * 16 + sub];
      uint2 u1 = xb2[(size_t)i1 * 16 + sub];
      uint2 u2 = xb2[(size_t)i2 * 16 + sub];
      uint2 u3 = xb2[(size_t)i3 * 16 + sub];
      if (e0 >= dg) { u0.x = 0u; u0.y = 0u; }
      if (e1 >= dg) { u1.x = 0u; u1.y = 0u; }
      if (e2 >= dg) { u2.x = 0u; u2.y = 0u; }
      if (e3 >= dg) { u3.x = 0u; u3.y = 0u; }
      a0 += (__uint_as_float(u0.x << 16) + __uint_as_float(u1.x << 16))
          + (__uint_as_float(u2.x << 16) + __uint_as_float(u3.x << 16));
      a1 += (__uint_as_float(u0.x & 0xFFFF0000u) + __uint_as_float(u1.x & 0xFFFF0000u))
          + (__uint_as_float(u2.x & 0xFFFF0000u) + __uint_as_float(u3.x & 0xFFFF0000u));
      a2 += (__uint_as_float(u0.y << 16) + __uint_as_float(u1.y << 16))
          + (__uint_as_float(u2.y << 16) + __uint_as_float(u3.y << 16));
      a3 += (__uint_as_float(u0.y & 0xFFFF0000u) + __uint_as_float(u1.y & 0xFFFF0000u))
          + (__uint_as_float(u2.y & 0xFFFF0000u) + __uint_as_float(u3.y & 0xFFFF0000u));
    }
#pragma unroll
    for (int off = 16; off <= 32; off <<= 1) {
      a0 += __shfl_xor(a0, off);
      a1 += __shfl_xor(a1, off);
      a2 += __shfl_xor(a2, off);
      a3 += __shfl_xor(a3, off);
    }
    if (g == 0) {
      float inv = 1.f / fmaxf((float)dg, 1.f);
      uint2 pw;
      pw.x = pk2(a0 * inv, a1 * inv);
      pw.y = pk2(a2 * inv, a3 * inv);
      uint rr = (uint)r;
      *(uint2*)((char*)As + rr * 256u + ((128u + (uint)sub * 8u) ^ ((rr & 7u) << 4))) = pw;
    }
  }
  __syncthreads();
  // MFMA combine: wave -> (mrow, n-tile pair); B fragments streamed from global (L2-hot),
  // unroll 1 keeps the loads in-loop so peak VGPR stays within the 8-blocks/CU budget.
  f32x4 acc0 = {0.f, 0.f, 0.f, 0.f}, acc1 = {0.f, 0.f, 0.f, 0.f};
  uint mrow  = (uint)(wl >> 1) << 4;   // 0 / 16
  int  nt    = wl & 1;
  uint arow  = mrow + (uint)(lane & 15);
  uint kc    = ((uint)(lane >> 4)) * 16u;   // byte offset of this lane's k-chunk
#pragma unroll 1
  for (int ks = 0; ks < 4; ++ks) {
    uint kb = (uint)ks * 64u + kc;
    bf16x8 af = *(const bf16x8*)((const char*)As + arow * 256u + (kb ^ ((arow & 7u) << 4)));
    bf16x8 b0 = *(const bf16x8*)(wtf + (size_t)(((nt * 2 + 0) * 4 + ks) * 64 + lane) * 8);
    bf16x8 b1 = *(const bf16x8*)(wtf + (size_t)(((nt * 2 + 1) * 4 + ks) * 64 + lane) * 8);
    acc0 = __builtin_amdgcn_mfma_f32_16x16x32_bf16(af, b0, acc0, 0, 0, 0);
    acc1 = __builtin_amdgcn_mfma_f32_16x16x32_bf16(af, b1, acc1, 0, 0, 0);
  }
  // write C to its own padded buffer (As stays live for the residual)
  {
    uint nbase = (uint)nt << 5;
    uint rr = mrow + (((uint)(lane >> 4)) << 2);
    uint cc = nbase + (uint)(lane & 15);
#pragma unroll
    for (int j = 0; j < 4; ++j) {
      uint rj = rr + (uint)j;
      Cbuf[rj * 65u + cc]       = acc0[j];
      Cbuf[rj * 65u + cc + 16u] = acc1[j];
    }
  }
  __syncthreads();
  // epilogue: bias, graph pooling (sorted batch), residual (bf16 x from LDS), LN, ReLU
  float bv  = bvec[lane];
  float gv  = gamma[lane];
  float btv = beta[lane];
  int r0 = wl * 8;
  int gprev = -1; float pool = 0.f;
#pragma unroll
  for (int m = 0; m < 8; ++m) {
    uint r = (uint)(r0 + m);
    int node = node0 + r0 + m;
    float cval = Cbuf[r * 65u + (uint)lane];
    float tmp = cval + bv;
    int gi = batch[node];
    if (gi != gprev) {
      if (gprev >= 0) atomicAdd(&gacc[gprev * DD + lane], pool);
      pool = 0.f; gprev = gi;
    }
    pool += tmp;
    ushort xv16 = *(const ushort*)((const char*)As + r * 256u + (((uint)lane * 2u) ^ ((r & 7u) << 4)));
    float val = tmp + __uint_as_float((uint)xv16 << 16);
    float s = val;
    for (int off = 32; off; off >>= 1) s += __shfl_xor(s, off);
    float mu  = s * (1.f / 64.f);
    float dlt = val - mu;
    float ss  = dlt * dlt;
    for (int off = 32; off; off >>= 1) ss += __shfl_xor(ss, off);
    float rstd = rsqrtf(ss * (1.f / 64.f) + EPSV);
    float o = dlt * rstd * gv + btv;
    out[(size_t)node * DD + lane] = fmaxf(o, 0.f);
  }
  if (gprev >= 0) atomicAdd(&gacc[gprev * DD + lane], pool);
}

__global__ __launch_bounds__(256) void graph_k(const float* __restrict__ gacc, const float* __restrict__ gemb,
                                               const float* __restrict__ gamma, const float* __restrict__ beta,
                                               float* __restrict__ out) {
  int lane = threadIdx.x & 63;
  int w = blockIdx.x * 4 + (threadIdx.x >> 6);
  if (w >= N_GRAPHS) return;
  float v = gacc[w * DD + lane] + gemb[w * DD + lane];
  float gv = gamma[lane], btv = beta[lane];
#pragma unroll
  for (int it = 0; it < 2; ++it) {
    float s = v;
    for (int off = 32; off; off >>= 1) s += __shfl_xor(s, off);
    float mu  = s * (1.f / 64.f);
    float d   = v - mu;
    float ss  = d * d;
    for (int off = 32; off; off >>= 1) ss += __shfl_xor(ss, off);
    v = d * rsqrtf(ss * (1.f / 64.f) + EPSV) * gv + btv;
  }
  out[(size_t)N_NODES * DD + w * DD + lane] = v;
}

extern "C" void kernel_launch(void* const* d_in, const int* in_sizes, int n_in,
                              void* d_out, int out_size, void* d_ws, size_t ws_size,
                              hipStream_t stream) {
  const float* x      = (const float*)d_in[0];
  const int*   ei     = (const int*)d_in[1];
  const int*   batch  = (const int*)d_in[2];
  const float* gemb   = (const float*)d_in[3];
  const float* Wself  = (const float*)d_in[4];
  const float* Wneigh = (const float*)d_in[5];
  const float* bvec   = (const float*)d_in[6];
  const float* gamma  = (const float*)d_in[7];
  const float* beta   = (const float*)d_in[8];

  char* ws = (char*)d_ws;
  int*    cur  = (int*)(ws + O_CUR);
  int*    bkt  = (int*)(ws + O_BKT);
  float*  gacc = (float*)(ws + O_GACC);
  ushort* xb   = (ushort*)(ws + O_XB);
  ushort* wtf  = (ushort*)(ws + O_WTF);
  float*  outf = (float*)d_out;

  cast_k <<<N_NODES * DD / 4 / 256, 256, 0, stream>>>(x, xb, cur, gacc);
  scatP_k<<<NBLK, THRP, 0, stream>>>(ei, cur, bkt, Wself, Wneigh, wtf);
  aggM_k <<<NBUCK, 256, 0, stream>>>(xb, cur, bkt, wtf, bvec, gamma, beta,
                                     batch, gacc, outf);
  graph_k<<<N_GRAPHS / 4, 256, 0, stream>>>(gacc, gemb, gamma, beta, outf);
}

// Round 15
// 92.825 us; speedup vs baseline: 1.1822x; 1.0271x over previous
//
#include <hip/hip_runtime.h>

#define N_NODES  100000
#define N_EDGES  1600000
#define N_GRAPHS 128
#define DD       64
#define EPSV     1e-5f

#define BSH      5          // bucket = dst >> 5  (32 nodes per bucket)
#define BMASK    31
#define NBUCK    3125       // 100000/32 exactly
#define CAPB     768        // slab capacity: mean 512, sigma 22.6 -> 11 sigma margin

#define THRP     1024       // scatter block threads
#define EPT      16         // edges per thread (98 blocks — known-good)
#define BLKE     (THRP*EPT) // 16384
#define NBLK     ((N_EDGES + BLKE - 1) / BLKE)   // 98

// workspace byte offsets
#define O_CUR   0u          // int[NBUCK*16]
#define O_BKT   200704u     // int[NBUCK*CAPB] packed (dstlo<<17)|src
#define O_GACC  9801216u    // float[G*D]; bytes [9833984,9834496) = zero row (gather tail target)
#define O_XB    9834496u    // ushort[N_NODES*DD]  bf16 copy of x
#define O_WTF   22634496u   // ushort[1024*8]  B-operand in MFMA fragment layout (16 KB)
#define WS_NEED (O_WTF + 16384u)

typedef __attribute__((ext_vector_type(8))) short bf16x8;
typedef __attribute__((ext_vector_type(4))) float f32x4;
typedef __attribute__((ext_vector_type(2))) float f32x2;

__device__ __forceinline__ ushort bf16rne(float f) {
  uint u = __float_as_uint(f);
  return (ushort)((u + 0x7FFFu + ((u >> 16) & 1u)) >> 16);
}
__device__ __forceinline__ uint pk2(float lo, float hi) {
  return (uint)bf16rne(lo) | ((uint)bf16rne(hi) << 16);
}

// full-grid fp32->bf16 cast of x + zero-init of cur, gacc, and the 512B zero row
__global__ __launch_bounds__(256) void cast_k(const float* __restrict__ x, ushort* __restrict__ xb,
                                              int* __restrict__ cur, float* __restrict__ gacc) {
  int i = blockIdx.x * 256 + threadIdx.x;      // grid 6250*256 = 1.6M = N_NODES*DD/4 exactly
  if (i < NBUCK * 16) cur[i] = 0;
  if (i < N_GRAPHS * DD) gacc[i] = 0.f;
  if (i < 128) gacc[N_GRAPHS * DD + i] = 0.f;  // zero row gap at ws+9833984 (= xb - 512)
  float4 v = ((const float4*)x)[i];
  uint4 u = *(const uint4*)&v;
  ushort4 o;
  o.x = (ushort)((u.x + 0x7FFFu + ((u.x >> 16) & 1)) >> 16);
  o.y = (ushort)((u.y + 0x7FFFu + ((u.y >> 16) & 1)) >> 16);
  o.z = (ushort)((u.z + 0x7FFFu + ((u.z >> 16) & 1)) >> 16);
  o.w = (ushort)((u.w + 0x7FFFu + ((u.w >> 16) & 1)) >> 16);
  ((ushort4*)xb)[i] = o;
}

// block-staged two-pass scatter; block 0 also builds the MFMA B-operand image wtf.
// hist[] reused in place: counts -> (after reservation) live slab cursor.
__global__ __launch_bounds__(1024) void scatP_k(const int* __restrict__ ei, int* __restrict__ cur,
                                                int* __restrict__ bkt,
                                                const float* __restrict__ Wself,
                                                const float* __restrict__ Wneigh,
                                                ushort* __restrict__ wtf) {
  __shared__ int hist[NBUCK];
  int t = threadIdx.x;
  if (blockIdx.x == 0) {
    // fragment f=(nt,tile,ks,lane): 8 bf16 of WT[nt*32+tile*16+(lane&15)][ks*32+(lane>>4)*8+j]
    int lane = t & 63, ks = (t >> 6) & 3, tile = (t >> 8) & 1, nt = t >> 9;
    int brow = (nt << 5) + (tile << 4) + (lane & 15);
    int k0 = (ks << 5) + (((lane >> 4) & 3) << 3);
    uint4 o;
    uint p[4];
#pragma unroll
    for (int jj = 0; jj < 4; ++jj) {
      int k = k0 + jj * 2;
      float w0 = (k < 64)     ? Wself[k * DD + brow]       : Wneigh[(k - 64) * DD + brow];
      float w1 = (k + 1 < 64) ? Wself[(k + 1) * DD + brow] : Wneigh[(k - 63) * DD + brow];
      p[jj] = pk2(w0, w1);
    }
    o.x = p[0]; o.y = p[1]; o.z = p[2]; o.w = p[3];
    ((uint4*)wtf)[t] = o;
  }
  for (int i = t; i < NBUCK; i += THRP) hist[i] = 0;
  __syncthreads();
  int e0 = blockIdx.x * BLKE;
  int pk[EPT], bn[EPT];
#pragma unroll
  for (int j = 0; j < EPT; ++j) {
    int e = e0 + j * THRP + t;
    bn[j] = -1;
    if (e < N_EDGES) {
      int s = ei[e], d = ei[N_EDGES + e];
      bn[j] = d >> BSH;
      pk[j] = s | ((d & BMASK) << 17);
      atomicAdd(&hist[bn[j]], 1);
    }
  }
  __syncthreads();
  for (int b = t; b < NBUCK; b += THRP) {     // each b handled by exactly one thread
    int c = hist[b];
    hist[b] = c ? atomicAdd(&cur[b * 16], c) : 0;   // count -> live slab cursor
  }
  __syncthreads();
#pragma unroll
  for (int j = 0; j < EPT; ++j) {
    if (bn[j] >= 0) {
      int sp = atomicAdd(&hist[bn[j]], 1);    // slab-relative position
      if (sp < CAPB) bkt[bn[j] * CAPB + sp] = pk[j];
    }
  }
}

// FUSED per-bucket kernel: counting-sort (premultiplied byte offsets) -> pull-based mean
// (zero-row tails, pk_add accumulate) -> MFMA combine (register B) -> epilogue.
__global__ __launch_bounds__(256, 8) void aggM_k(const ushort* __restrict__ xb,
                                                 const int* __restrict__ cur,
                                                 const int* __restrict__ bkt,
                                                 const ushort* __restrict__ wtf,
                                                 const float* __restrict__ bvec,
                                                 const float* __restrict__ gamma,
                                                 const float* __restrict__ beta,
                                                 const int* __restrict__ batch,
                                                 float* __restrict__ gacc,
                                                 float* __restrict__ out) {
  __shared__ short As[32 * 128];    // 8KB: A=[xb|h] bf16 swizzled; LIVE through epilogue
  __shared__ float Cbuf[32 * 65];   // 8.3KB: MFMA C, padded row stride (conflict-free reads)
  __shared__ int sorted[CAPB + 16]; // byte offsets (idx*128+512), +16 pad for tail reads
  __shared__ int hist[32], startc[32], curl[32];
  int t = threadIdx.x;
  int b = blockIdx.x;
  int node0 = b << BSH;
  if (t < 32) hist[t] = 0;
  // stage A x-part (k=0..63): contiguous 4KB read of this bucket's xb rows
  {
    uint4 v = ((const uint4*)(xb + (size_t)node0 * DD))[t];   // t = r*8 + c
    uint r = (uint)t >> 3, c = (uint)t & 7;
    *(uint4*)((char*)As + r * 256u + ((c * 16u) ^ ((r & 7u) << 4))) = v;
  }
  __syncthreads();
  int n = cur[b * 16];
  if (n > CAPB) n = CAPB;
  int boff = b * CAPB;
  int w0 = -1, w1 = -1, w2 = -1;
  if (t < n)       { w0 = bkt[boff + t];       atomicAdd(&hist[w0 >> 17], 1); }
  if (t + 256 < n) { w1 = bkt[boff + t + 256]; atomicAdd(&hist[w1 >> 17], 1); }
  if (t + 512 < n) { w2 = bkt[boff + t + 512]; atomicAdd(&hist[w2 >> 17], 1); }
  __syncthreads();
  // exclusive scan of 32 bins: wave-0 shuffle scan, ONE barrier (was 10)
  if (t < 32) {
    int h = hist[t];
    int v = h;
#pragma unroll
    for (int off = 1; off < 32; off <<= 1) {
      int u = __shfl_up(v, off);
      if (t >= off) v += u;
    }
    startc[t] = v - h;
    curl[t]   = v - h;
  }
  __syncthreads();
  if (w0 >= 0) { int p = atomicAdd(&curl[w0 >> 17], 1); sorted[p] = ((w0 & 0x1FFFF) << 7) + 512; }
  if (w1 >= 0) { int p = atomicAdd(&curl[w1 >> 17], 1); sorted[p] = ((w1 & 0x1FFFF) << 7) + 512; }
  if (w2 >= 0) { int p = atomicAdd(&curl[w2 >> 17], 1); sorted[p] = ((w2 & 0x1FFFF) << 7) + 512; }
  __syncthreads();
  int wl   = __builtin_amdgcn_readfirstlane(t >> 6);
  int lane = t & 63;
  int g    = lane >> 4;     // edge-group 0..3
  int sub  = lane & 15;     // dim group: dims [sub*4, sub*4+4)
  const char* zb = (const char*)xb - 512;   // base: +0 hits the zero row, +sorted hits xb
  uint subb = (uint)sub * 8u;
  // pull aggregation: 4 edges per instruction x 4 loads in flight; mean -> A k=64..127
  for (int r = wl; r < 32; r += 4) {
    int s0 = startc[r], dg = hist[r];
    f32x2 A01 = {0.f, 0.f}, A23 = {0.f, 0.f};
    for (int j = 0; j < dg; j += 16) {
      int e0 = j + g, e1 = j + 4 + g, e2 = j + 8 + g, e3 = j + 12 + g;
      uint o0 = (uint)sorted[s0 + e0]; if (e0 >= dg) o0 = 0u;   // tail -> zero row
      uint o1 = (uint)sorted[s0 + e1]; if (e1 >= dg) o1 = 0u;
      uint o2 = (uint)sorted[s0 + e2]; if (e2 >= dg) o2 = 0u;
      uint o3 = (uint)sorted[s0 + e3]; if (e3 >= dg) o3 = 0u;
      uint2 u0 = *(const uint2*)(zb + o0 + subb);               // 4 gathers in flight
      uint2 u1 = *(const uint2*)(zb + o1 + subb);
      uint2 u2 = *(const uint2*)(zb + o2 + subb);
      uint2 u3 = *(const uint2*)(zb + o3 + subb);
      f32x2 v0, v1, v2, v3, y0, y1, y2, y3;
      v0.x = __uint_as_float(u0.x << 16); v0.y = __uint_as_float(u0.x & 0xFFFF0000u);
      v1.x = __uint_as_float(u1.x << 16); v1.y = __uint_as_float(u1.x & 0xFFFF0000u);
      v2.x = __uint_as_float(u2.x << 16); v2.y = __uint_as_float(u2.x & 0xFFFF0000u);
      v3.x = __uint_as_float(u3.x << 16); v3.y = __uint_as_float(u3.x & 0xFFFF0000u);
      y0.x = __uint_as_float(u0.y << 16); y0.y = __uint_as_float(u0.y & 0xFFFF0000u);
      y1.x = __uint_as_float(u1.y << 16); y1.y = __uint_as_float(u1.y & 0xFFFF0000u);
      y2.x = __uint_as_float(u2.y << 16); y2.y = __uint_as_float(u2.y & 0xFFFF0000u);
      y3.x = __uint_as_float(u3.y << 16); y3.y = __uint_as_float(u3.y & 0xFFFF0000u);
      A01 += (v0 + v1) + (v2 + v3);
      A23 += (y0 + y1) + (y2 + y3);
    }
    float a0 = A01.x, a1 = A01.y, a2 = A23.x, a3 = A23.y;
    // merge the 4 edge-groups: butterfly over lane bits 4,5
#pragma unroll
    for (int off = 16; off <= 32; off <<= 1) {
      a0 += __shfl_xor(a0, off);
      a1 += __shfl_xor(a1, off);
      a2 += __shfl_xor(a2, off);
      a3 += __shfl_xor(a3, off);
    }
    if (g == 0) {
      float inv = 1.f / fmaxf((float)dg, 1.f);
      uint2 pw;
      pw.x = pk2(a0 * inv, a1 * inv);
      pw.y = pk2(a2 * inv, a3 * inv);
      uint rr = (uint)r;
      *(uint2*)((char*)As + rr * 256u + ((128u + (uint)sub * 8u) ^ ((rr & 7u) << 4))) = pw;
    }
  }
  __syncthreads();
  // MFMA combine: wave -> (mrow, n-tile pair); B fragments streamed from global (L2-hot),
  // unroll 1 keeps the loads in-loop so peak VGPR stays within the 8-blocks/CU budget.
  f32x4 acc0 = {0.f, 0.f, 0.f, 0.f}, acc1 = {0.f, 0.f, 0.f, 0.f};
  uint mrow  = (uint)(wl >> 1) << 4;   // 0 / 16
  int  nt    = wl & 1;
  uint arow  = mrow + (uint)(lane & 15);
  uint kc    = ((uint)(lane >> 4)) * 16u;   // byte offset of this lane's k-chunk
#pragma unroll 1
  for (int ks = 0; ks < 4; ++ks) {
    uint kb = (uint)ks * 64u + kc;
    bf16x8 af = *(const bf16x8*)((const char*)As + arow * 256u + (kb ^ ((arow & 7u) << 4)));
    bf16x8 b0 = *(const bf16x8*)(wtf + (size_t)(((nt * 2 + 0) * 4 + ks) * 64 + lane) * 8);
    bf16x8 b1 = *(const bf16x8*)(wtf + (size_t)(((nt * 2 + 1) * 4 + ks) * 64 + lane) * 8);
    acc0 = __builtin_amdgcn_mfma_f32_16x16x32_bf16(af, b0, acc0, 0, 0, 0);
    acc1 = __builtin_amdgcn_mfma_f32_16x16x32_bf16(af, b1, acc1, 0, 0, 0);
  }
  // write C to its own padded buffer (As stays live for the residual)
  {
    uint nbase = (uint)nt << 5;
    uint rr = mrow + (((uint)(lane >> 4)) << 2);
    uint cc = nbase + (uint)(lane & 15);
#pragma unroll
    for (int j = 0; j < 4; ++j) {
      uint rj = rr + (uint)j;
      Cbuf[rj * 65u + cc]       = acc0[j];
      Cbuf[rj * 65u + cc + 16u] = acc1[j];
    }
  }
  __syncthreads();
  // epilogue: bias, graph pooling (sorted batch), residual (bf16 x from LDS), LN, ReLU
  float bv  = bvec[lane];
  float gv  = gamma[lane];
  float btv = beta[lane];
  int r0 = wl * 8;
  int gprev = -1; float pool = 0.f;
#pragma unroll
  for (int m = 0; m < 8; ++m) {
    uint r = (uint)(r0 + m);
    int node = node0 + r0 + m;
    float cval = Cbuf[r * 65u + (uint)lane];
    float tmp = cval + bv;
    int gi = batch[node];
    if (gi != gprev) {
      if (gprev >= 0) atomicAdd(&gacc[gprev * DD + lane], pool);
      pool = 0.f; gprev = gi;
    }
    pool += tmp;
    ushort xv16 = *(const ushort*)((const char*)As + r * 256u + (((uint)lane * 2u) ^ ((r & 7u) << 4)));
    float val = tmp + __uint_as_float((uint)xv16 << 16);
    float s = val;
    for (int off = 32; off; off >>= 1) s += __shfl_xor(s, off);
    float mu  = s * (1.f / 64.f);
    float dlt = val - mu;
    float ss  = dlt * dlt;
    for (int off = 32; off; off >>= 1) ss += __shfl_xor(ss, off);
    float rstd = rsqrtf(ss * (1.f / 64.f) + EPSV);
    float o = dlt * rstd * gv + btv;
    out[(size_t)node * DD + lane] = fmaxf(o, 0.f);
  }
  if (gprev >= 0) atomicAdd(&gacc[gprev * DD + lane], pool);
}

__global__ __launch_bounds__(256) void graph_k(const float* __restrict__ gacc, const float* __restrict__ gemb,
                                               const float* __restrict__ gamma, const float* __restrict__ beta,
                                               float* __restrict__ out) {
  int lane = threadIdx.x & 63;
  int w = blockIdx.x * 4 + (threadIdx.x >> 6);
  if (w >= N_GRAPHS) return;
  float v = gacc[w * DD + lane] + gemb[w * DD + lane];
  float gv = gamma[lane], btv = beta[lane];
#pragma unroll
  for (int it = 0; it < 2; ++it) {
    float s = v;
    for (int off = 32; off; off >>= 1) s += __shfl_xor(s, off);
    float mu  = s * (1.f / 64.f);
    float d   = v - mu;
    float ss  = d * d;
    for (int off = 32; off; off >>= 1) ss += __shfl_xor(ss, off);
    v = d * rsqrtf(ss * (1.f / 64.f) + EPSV) * gv + btv;
  }
  out[(size_t)N_NODES * DD + w * DD + lane] = v;
}

extern "C" void kernel_launch(void* const* d_in, const int* in_sizes, int n_in,
                              void* d_out, int out_size, void* d_ws, size_t ws_size,
                              hipStream_t stream) {
  const float* x      = (const float*)d_in[0];
  const int*   ei     = (const int*)d_in[1];
  const int*   batch  = (const int*)d_in[2];
  const float* gemb   = (const float*)d_in[3];
  const float* Wself  = (const float*)d_in[4];
  const float* Wneigh = (const float*)d_in[5];
  const float* bvec   = (const float*)d_in[6];
  const float* gamma  = (const float*)d_in[7];
  const float* beta   = (const float*)d_in[8];

  char* ws = (char*)d_ws;
  int*    cur  = (int*)(ws + O_CUR);
  int*    bkt  = (int*)(ws + O_BKT);
  float*  gacc = (float*)(ws + O_GACC);
  ushort* xb   = (ushort*)(ws + O_XB);
  ushort* wtf  = (ushort*)(ws + O_WTF);
  float*  outf = (float*)d_out;

  cast_k <<<N_NODES * DD / 4 / 256, 256, 0, stream>>>(x, xb, cur, gacc);
  scatP_k<<<NBLK, THRP, 0, stream>>>(ei, cur, bkt, Wself, Wneigh, wtf);
  aggM_k <<<NBUCK, 256, 0, stream>>>(xb, cur, bkt, wtf, bvec, gamma, beta,
                                     batch, gacc, outf);
  graph_k<<<N_GRAPHS / 4, 256, 0, stream>>>(gacc, gemb, gamma, beta, outf);
}